// Round 1
// baseline (855.890 us; speedup 1.0000x reference)
//
#include <hip/hip_runtime.h>
#include <stdint.h>

typedef unsigned short u16;
typedef __attribute__((ext_vector_type(8))) short bf16x8;
typedef __attribute__((ext_vector_type(4))) short s16x4;
typedef __attribute__((ext_vector_type(4))) float f32x4;

#define DEV __device__ __forceinline__

DEV u16 f2bf(float f) {
  union { float f; unsigned u; } v; v.f = f;
  unsigned r = v.u + 0x7fffu + ((v.u >> 16) & 1u);
  return (u16)(r >> 16);
}
DEV int imax(int a, int b) { return a > b ? a : b; }
DEV int imin(int a, int b) { return a < b ? a : b; }

// ---------------------------------------------------------------------------
// f32 -> bf16 cast (vectorized x4)
// ---------------------------------------------------------------------------
__global__ __launch_bounds__(256) void cast_kernel(const float* __restrict__ in,
                                                   u16* __restrict__ out, int n4) {
  int idx = blockIdx.x * 256 + threadIdx.x;
  if (idx >= n4) return;
  f32x4 f = ((const f32x4*)in)[idx];
  s16x4 o;
  o.x = (short)f2bf(f.x);
  o.y = (short)f2bf(f.y);
  o.z = (short)f2bf(f.z);
  o.w = (short)f2bf(f.w);
  ((s16x4*)out)[idx] = o;
}

// ---------------------------------------------------------------------------
// bf16 GEMM: C[m,n] = act(scale * sum_k A[m,k]*W[n,k] + bias[n])
// A: [M,K] bf16 row-major, W: [Nn,K] bf16 row-major (torch Linear weight).
// 128x128 tile per block (256 thr = 4 waves, each wave 64x64 via 4x4 MFMA).
// M, Nn multiples of 128; K multiple of 32.
// ---------------------------------------------------------------------------
__global__ __launch_bounds__(256) void gemm_bf16(
    const u16* __restrict__ A, const u16* __restrict__ W,
    float* __restrict__ C, const float* __restrict__ bias,
    int M, int Nn, int K, float scale, int relu) {
  __shared__ u16 As[128 * 32];
  __shared__ u16 Ws[128 * 32];
  const int tid = threadIdx.x;
  const int lane = tid & 63;
  const int wave = tid >> 6;
  const int m0 = blockIdx.x * 128;
  const int n0 = blockIdx.y * 128;
  const int wm = (wave >> 1) * 64;
  const int wn = (wave & 1) * 64;

  f32x4 acc[4][4] = {};

  for (int k0 = 0; k0 < K; k0 += 32) {
    // stage A-tile and W-tile: 512 chunks of 16B each
#pragma unroll
    for (int hh = 0; hh < 2; ++hh) {
      int c = tid + hh * 256;
      int row = c >> 2, part = c & 3;
      const u16* ga = A + (size_t)(m0 + row) * K + (k0 + part * 8);
      const u16* gw = W + (size_t)(n0 + row) * K + (k0 + part * 8);
      bf16x8 va = *(const bf16x8*)ga;
      bf16x8 vw = *(const bf16x8*)gw;
      *(bf16x8*)(As + c * 8) = va;
      *(bf16x8*)(Ws + c * 8) = vw;
    }
    __syncthreads();
    bf16x8 af[4], bfr[4];
#pragma unroll
    for (int t = 0; t < 4; ++t)
      af[t] = *(const bf16x8*)(As + (wm + t * 16 + (lane & 15)) * 32 + (lane >> 4) * 8);
#pragma unroll
    for (int t = 0; t < 4; ++t)
      bfr[t] = *(const bf16x8*)(Ws + (wn + t * 16 + (lane & 15)) * 32 + (lane >> 4) * 8);
#pragma unroll
    for (int mi = 0; mi < 4; ++mi)
#pragma unroll
      for (int ni = 0; ni < 4; ++ni)
        acc[mi][ni] = __builtin_amdgcn_mfma_f32_16x16x32_bf16(af[mi], bfr[ni], acc[mi][ni], 0, 0, 0);
    __syncthreads();
  }

  // epilogue: C/D layout col = lane&15, row = (lane>>4)*4 + r
#pragma unroll
  for (int mi = 0; mi < 4; ++mi) {
#pragma unroll
    for (int ni = 0; ni < 4; ++ni) {
      int col = n0 + wn + ni * 16 + (lane & 15);
      float bv = bias ? bias[col] : 0.f;
#pragma unroll
      for (int r = 0; r < 4; ++r) {
        int row = m0 + wm + mi * 16 + (lane >> 4) * 4 + r;
        float vv = acc[mi][ni][r] * scale + bv;
        if (relu) vv = fmaxf(vv, 0.f);
        C[(size_t)row * Nn + col] = vv;
      }
    }
  }
}

// ---------------------------------------------------------------------------
// Banded attention: logits (fp32 dot), softmax over |i-j|<20 band.
// One wave per row i (4 rows / block). Writes att into d_out att region
// (full row already zeroed by memset) and dense band buffer [N,40].
// ---------------------------------------------------------------------------
template <int DIM>
__global__ __launch_bounds__(256) void banded_attn_kernel(
    const float* __restrict__ Q, const float* __restrict__ K,
    float* __restrict__ attBase, float* __restrict__ band,
    int N, int attStride, int colOff) {
  constexpr int VPL = DIM / 64;  // elems per lane
  __shared__ float red[4][64][40];
  const int tid = threadIdx.x;
  const int lane = tid & 63;
  const int wave = tid >> 6;
  const int i = blockIdx.x * 4 + wave;

  float q[VPL];
#pragma unroll
  for (int u = 0; u < VPL; ++u) q[u] = Q[(size_t)i * DIM + lane * VPL + u];

  const int lo = imax(i - 19, 0);
  const int hi = imin(i + 19, N - 1);
  const int nj = hi - lo + 1;

#pragma unroll 1
  for (int s = 0; s < 39; ++s) {
    float p = 0.f;
    if (s < nj) {
      const float* krow = K + (size_t)(lo + s) * DIM + lane * VPL;
#pragma unroll
      for (int u = 0; u < VPL; ++u) p += q[u] * krow[u];
    }
    red[wave][lane][s] = p;
  }
  __syncthreads();

  float logit = -3.4e38f;
  if (lane < nj) {
    float ssum = 0.f;
#pragma unroll 1
    for (int l = 0; l < 64; ++l) ssum += red[wave][l][lane];
    logit = ssum;
  }
  float mx = logit;
#pragma unroll
  for (int off = 32; off; off >>= 1) mx = fmaxf(mx, __shfl_xor(mx, off));
  float e = (lane < nj) ? __expf(logit - mx) : 0.f;
  float den = e;
#pragma unroll
  for (int off = 32; off; off >>= 1) den += __shfl_xor(den, off);
  float att = e / den;
  if (lane < nj) {
    attBase[(size_t)i * attStride + colOff + lo + lane] = att;
    band[i * 40 + lane] = att;
  }
}

// ---------------------------------------------------------------------------
// y[j,:] = sum_i att[i,j] * V[i,:]  (att.T @ V), band only. Output bf16.
// One block per output row j.
// ---------------------------------------------------------------------------
template <int DIM, int BLK>
__global__ __launch_bounds__(BLK) void apply_attn_kernel(
    const float* __restrict__ V, const float* __restrict__ band,
    u16* __restrict__ Y, int N) {
  constexpr int CPT = DIM / BLK;
  const int j = blockIdx.x;
  const int tid = threadIdx.x;
  __shared__ float a_sh[40];
  const int lo = imax(j - 19, 0);
  const int hi = imin(j + 19, N - 1);
  const int ni = hi - lo + 1;
  if (tid < ni) {
    int i = lo + tid;
    int lo_i = imax(i - 19, 0);
    a_sh[tid] = band[i * 40 + (j - lo_i)];
  }
  __syncthreads();
  float acc[CPT];
#pragma unroll
  for (int u = 0; u < CPT; ++u) acc[u] = 0.f;
#pragma unroll 1
  for (int s = 0; s < ni; ++s) {
    float a = a_sh[s];
    const float* vrow = V + (size_t)(lo + s) * DIM + tid;
#pragma unroll
    for (int u = 0; u < CPT; ++u) acc[u] += a * vrow[u * BLK];
  }
#pragma unroll
  for (int u = 0; u < CPT; ++u)
    Y[(size_t)j * DIM + tid + u * BLK] = f2bf(acc[u]);
}

// ---------------------------------------------------------------------------
// LayerNorm(O + X) * g + b  -> bf16 output at [row*outStride + outOff + c]
// ---------------------------------------------------------------------------
template <int DIM, int BLK>
__global__ __launch_bounds__(BLK) void ln_res_kernel(
    const float* __restrict__ O, const float* __restrict__ X,
    const float* __restrict__ g, const float* __restrict__ bb,
    u16* __restrict__ out, int outStride, int outOff) {
  constexpr int CPT = DIM / BLK;
  constexpr int NW = BLK / 64;
  const int row = blockIdx.x;
  const int tid = threadIdx.x, lane = tid & 63, wave = tid >> 6;
  __shared__ float shA[NW], shB[NW];
  float v[CPT];
  float s = 0.f, s2 = 0.f;
#pragma unroll
  for (int u = 0; u < CPT; ++u) {
    int c = tid + u * BLK;
    v[u] = O[(size_t)row * DIM + c] + X[(size_t)row * DIM + c];
    s += v[u];
    s2 += v[u] * v[u];
  }
#pragma unroll
  for (int off = 32; off; off >>= 1) {
    s += __shfl_xor(s, off);
    s2 += __shfl_xor(s2, off);
  }
  if (lane == 0) { shA[wave] = s; shB[wave] = s2; }
  __syncthreads();
  float S = shA[0], S2 = shB[0];
#pragma unroll
  for (int w2 = 1; w2 < NW; ++w2) { S += shA[w2]; S2 += shB[w2]; }
  float mu = S / DIM;
  float var = S2 / DIM - mu * mu;
  float inv = rsqrtf(var + 1e-6f);
#pragma unroll
  for (int u = 0; u < CPT; ++u) {
    int c = tid + u * BLK;
    float o = (v[u] - mu) * inv * g[c] + bb[c];
    out[(size_t)row * outStride + outOff + c] = f2bf(o);
  }
}

// ---------------------------------------------------------------------------
// head: score[row] = sigmoid( LN(H[row]) . kw + kb )
// ---------------------------------------------------------------------------
__global__ __launch_bounds__(256) void head_kernel(
    const float* __restrict__ H, const float* __restrict__ g,
    const float* __restrict__ bb, const float* __restrict__ kw,
    const float* __restrict__ kb, float* __restrict__ score) {
  const int row = blockIdx.x;
  const int tid = threadIdx.x, lane = tid & 63, wave = tid >> 6;
  __shared__ float shA[4], shB[4];
  float v[4];
  float s = 0.f, s2 = 0.f;
#pragma unroll
  for (int u = 0; u < 4; ++u) {
    int c = tid + u * 256;
    v[u] = H[(size_t)row * 1024 + c];
    s += v[u];
    s2 += v[u] * v[u];
  }
#pragma unroll
  for (int off = 32; off; off >>= 1) {
    s += __shfl_xor(s, off);
    s2 += __shfl_xor(s2, off);
  }
  if (lane == 0) { shA[wave] = s; shB[wave] = s2; }
  __syncthreads();
  float S = shA[0] + shA[1] + shA[2] + shA[3];
  float S2 = shB[0] + shB[1] + shB[2] + shB[3];
  float mu = S / 1024.f;
  float var = S2 / 1024.f - mu * mu;
  float inv = rsqrtf(var + 1e-6f);
  float p = 0.f;
#pragma unroll
  for (int u = 0; u < 4; ++u) {
    int c = tid + u * 256;
    p += ((v[u] - mu) * inv * g[c] + bb[c]) * kw[c];
  }
#pragma unroll
  for (int off = 32; off; off >>= 1) p += __shfl_xor(p, off);
  __syncthreads();
  if (lane == 0) shA[wave] = p;
  __syncthreads();
  if (tid == 0) {
    float P = shA[0] + shA[1] + shA[2] + shA[3] + kb[0];
    score[row] = 1.f / (1.f + __expf(-P));
  }
}

// ---------------------------------------------------------------------------
extern "C" void kernel_launch(void* const* d_in, const int* in_sizes, int n_in,
                              void* d_out, int out_size, void* d_ws, size_t ws_size,
                              hipStream_t stream) {
  const float* x = (const float*)d_in[0];     // [N,1024]
  const float* xa = (const float*)d_in[1];    // [N,128]
  const float* Wk_v = (const float*)d_in[4];
  const float* Wq_v = (const float*)d_in[5];
  const float* Wv_v = (const float*)d_in[6];
  const float* Wo_v = (const float*)d_in[7];
  const float* Wk_a = (const float*)d_in[8];
  const float* Wq_a = (const float*)d_in[9];
  const float* Wv_a = (const float*)d_in[10];
  const float* Wo_a = (const float*)d_in[11];
  const float* ka_w = (const float*)d_in[12];  // [1024,1152]
  const float* ka_b = (const float*)d_in[13];
  const float* kd_w = (const float*)d_in[14];  // [1,1024]
  const float* kd_b = (const float*)d_in[15];
  const float* ln_y_g = (const float*)d_in[16];
  const float* ln_y_b = (const float*)d_in[17];
  const float* ln_ya_g = (const float*)d_in[18];
  const float* ln_ya_b = (const float*)d_in[19];
  const float* ln_ka_g = (const float*)d_in[20];
  const float* ln_ka_b = (const float*)d_in[21];

  const int N = in_sizes[0] / 1024;  // 6144
  const int MV = 1024, MA = 128, MH = 1152;

  // workspace layout
  char* wsb = (char*)d_ws;
  size_t off = 0;
  auto alloc = [&](size_t bytes) -> void* {
    void* p = wsb + off;
    off += (bytes + 255) & ~(size_t)255;
    return p;
  };
  u16* xf_b  = (u16*)alloc((size_t)N * MV * 2);
  u16* xa_b  = (u16*)alloc((size_t)N * MA * 2);
  u16* wkv_b = (u16*)alloc((size_t)MV * MV * 2);
  u16* wqv_b = (u16*)alloc((size_t)MV * MV * 2);
  u16* wvv_b = (u16*)alloc((size_t)MV * MV * 2);
  u16* wov_b = (u16*)alloc((size_t)MV * MV * 2);
  u16* wka_b = (u16*)alloc((size_t)MA * MA * 2);
  u16* wqa_b = (u16*)alloc((size_t)MA * MA * 2);
  u16* wva_b = (u16*)alloc((size_t)MA * MA * 2);
  u16* woa_b = (u16*)alloc((size_t)MA * MA * 2);
  u16* kaw_b = (u16*)alloc((size_t)1024 * MH * 2);
  float* Qv = (float*)alloc((size_t)N * MV * 4);
  float* Kv = (float*)alloc((size_t)N * MV * 4);
  float* Vv = (float*)alloc((size_t)N * MV * 4);
  float* Qa = (float*)alloc((size_t)N * MA * 4);
  float* Ka = (float*)alloc((size_t)N * MA * 4);
  float* Va = (float*)alloc((size_t)N * MA * 4);
  float* bandV = (float*)alloc((size_t)N * 40 * 4);
  float* bandA = (float*)alloc((size_t)N * 40 * 4);
  u16* yv_b = (u16*)alloc((size_t)N * MV * 2);
  u16* ya_b = (u16*)alloc((size_t)N * MA * 2);
  float* ov = (float*)alloc((size_t)N * MV * 4);  // reused as h after LN
  float* oa = (float*)alloc((size_t)N * MA * 4);
  u16* ycomb_b = (u16*)alloc((size_t)N * MH * 2);
  float* h = ov;  // safe: ov fully consumed by ln_res before h GEMM

  float* dout = (float*)d_out;
  float* attBase = dout + N;  // att_comb [N, 2N] after score [N]

  // 1) zero d_out (att outside band must be 0; score overwritten later)
  hipMemsetAsync(d_out, 0, (size_t)out_size * sizeof(float), stream);

  // 2) casts to bf16
  auto cast = [&](const float* src, u16* dst, size_t n) {
    int n4 = (int)(n / 4);
    cast_kernel<<<(n4 + 255) / 256, 256, 0, stream>>>(src, dst, n4);
  };
  cast(x, xf_b, (size_t)N * MV);
  cast(xa, xa_b, (size_t)N * MA);
  cast(Wk_v, wkv_b, (size_t)MV * MV);
  cast(Wq_v, wqv_b, (size_t)MV * MV);
  cast(Wv_v, wvv_b, (size_t)MV * MV);
  cast(Wo_v, wov_b, (size_t)MV * MV);
  cast(Wk_a, wka_b, (size_t)MA * MA);
  cast(Wq_a, wqa_b, (size_t)MA * MA);
  cast(Wv_a, wva_b, (size_t)MA * MA);
  cast(Wo_a, woa_b, (size_t)MA * MA);
  cast(ka_w, kaw_b, (size_t)1024 * MH);

  // 3) QKV projections
  dim3 gv(N / 128, MV / 128);
  dim3 ga(N / 128, MA / 128);
  gemm_bf16<<<gv, 256, 0, stream>>>(xf_b, wkv_b, Kv, nullptr, N, MV, MV, 1.f, 0);
  gemm_bf16<<<gv, 256, 0, stream>>>(xf_b, wqv_b, Qv, nullptr, N, MV, MV, 0.06f, 0);
  gemm_bf16<<<gv, 256, 0, stream>>>(xf_b, wvv_b, Vv, nullptr, N, MV, MV, 1.f, 0);
  gemm_bf16<<<ga, 256, 0, stream>>>(xa_b, wka_b, Ka, nullptr, N, MA, MA, 1.f, 0);
  gemm_bf16<<<ga, 256, 0, stream>>>(xa_b, wqa_b, Qa, nullptr, N, MA, MA, 0.06f, 0);
  gemm_bf16<<<ga, 256, 0, stream>>>(xa_b, wva_b, Va, nullptr, N, MA, MA, 1.f, 0);

  // 4) banded softmax attention (writes att into d_out + band buffer)
  banded_attn_kernel<1024><<<N / 4, 256, 0, stream>>>(Qv, Kv, attBase, bandV, N, 2 * N, 0);
  banded_attn_kernel<128><<<N / 4, 256, 0, stream>>>(Qa, Ka, attBase, bandA, N, 2 * N, N);

  // 5) y = att.T @ V  (bf16 out)
  apply_attn_kernel<1024, 256><<<N, 256, 0, stream>>>(Vv, bandV, yv_b, N);
  apply_attn_kernel<128, 128><<<N, 128, 0, stream>>>(Va, bandA, ya_b, N);

  // 6) output projections
  gemm_bf16<<<gv, 256, 0, stream>>>(yv_b, wov_b, ov, nullptr, N, MV, MV, 1.f, 0);
  gemm_bf16<<<ga, 256, 0, stream>>>(ya_b, woa_b, oa, nullptr, N, MA, MA, 1.f, 0);

  // 7) LN(o + x) -> ycomb (bf16, concat columns)
  ln_res_kernel<1024, 256><<<N, 256, 0, stream>>>(ov, x, ln_y_g, ln_y_b, ycomb_b, MH, 0);
  ln_res_kernel<128, 128><<<N, 128, 0, stream>>>(oa, xa, ln_ya_g, ln_ya_b, ycomb_b, MH, 1024);

  // 8) h = relu(ycomb @ ka_w.T + ka_b)
  dim3 gh(N / 128, 1024 / 128);
  gemm_bf16<<<gh, 256, 0, stream>>>(ycomb_b, kaw_b, h, ka_b, N, 1024, MH, 1.f, 1);

  // 9) score = sigmoid(LN(h) . kd_w + kd_b)
  head_kernel<<<N, 256, 0, stream>>>(h, ln_ka_g, ln_ka_b, kd_w, kd_b, dout);
}

// Round 2
// 770.830 us; speedup vs baseline: 1.1103x; 1.1103x over previous
//
#include <hip/hip_runtime.h>
#include <stdint.h>

typedef unsigned short u16;
typedef unsigned int u32;
typedef __attribute__((ext_vector_type(8))) short bf16x8;
typedef __attribute__((ext_vector_type(4))) short s16x4;
typedef __attribute__((ext_vector_type(4))) float f32x4;
typedef __attribute__((ext_vector_type(2))) float f32x2;

#define DEV __device__ __forceinline__

DEV u16 f2bf(float f) {
  union { float f; unsigned u; } v; v.f = f;
  unsigned r = v.u + 0x7fffu + ((v.u >> 16) & 1u);
  return (u16)(r >> 16);
}
DEV int imax(int a, int b) { return a > b ? a : b; }
DEV int imin(int a, int b) { return a < b ? a : b; }

// async global->LDS, 16 bytes per lane; LDS dest = wave-uniform base + lane*16
DEV void g2lds16(const u16* g, u16* l) {
  __builtin_amdgcn_global_load_lds(
      (const __attribute__((address_space(1))) void*)g,
      (__attribute__((address_space(3))) void*)l, 16, 0, 0);
}

// ---------------------------------------------------------------------------
// f32 -> bf16 cast (x4)
// ---------------------------------------------------------------------------
__global__ __launch_bounds__(256) void cast_kernel(const float* __restrict__ in,
                                                   u16* __restrict__ out, int n4) {
  int idx = blockIdx.x * 256 + threadIdx.x;
  if (idx >= n4) return;
  f32x4 f = ((const f32x4*)in)[idx];
  s16x4 o;
  o.x = (short)f2bf(f.x);
  o.y = (short)f2bf(f.y);
  o.z = (short)f2bf(f.z);
  o.w = (short)f2bf(f.w);
  ((s16x4*)out)[idx] = o;
}

// pack three same-shape fp32 weights -> one bf16 buffer [3*rows, cols]
__global__ __launch_bounds__(256) void cast3_kernel(
    const float* __restrict__ a, const float* __restrict__ b,
    const float* __restrict__ c, u16* __restrict__ dst, int n4each) {
  int idx = blockIdx.x * 256 + threadIdx.x;
  if (idx >= 3 * n4each) return;
  const float* src;
  int local;
  if (idx < n4each) { src = a; local = idx; }
  else if (idx < 2 * n4each) { src = b; local = idx - n4each; }
  else { src = c; local = idx - 2 * n4each; }
  f32x4 f = ((const f32x4*)src)[local];
  s16x4 o;
  o.x = (short)f2bf(f.x);
  o.y = (short)f2bf(f.y);
  o.z = (short)f2bf(f.z);
  o.w = (short)f2bf(f.w);
  ((s16x4*)dst)[idx] = o;
}

// ---------------------------------------------------------------------------
// bf16 GEMM (m97 structure): C[m,n] = act(sum_k A[m,k]*W[n,k] + bias[n])
// A:[M,K] bf16 rm, W:[Nn,K] bf16 rm. 128x128 tile, 4 waves x (64x64 via 4x4
// 16x16x32 MFMA). global_load_lds width-16 staging. M%128==0, Nn%128==0,
// K%32==0, rows 16B-aligned.
// ---------------------------------------------------------------------------
__global__ __launch_bounds__(256) void gemm_bf16(
    const u16* __restrict__ A, const u16* __restrict__ W,
    float* __restrict__ C, const float* __restrict__ bias,
    int M, int Nn, int K, int relu) {
  __shared__ u16 As[128 * 32];
  __shared__ u16 Ws[128 * 32];
  const int tid = threadIdx.x;
  const int lane = tid & 63;
  const int wave = tid >> 6;
  const int m0 = blockIdx.x * 128;
  const int n0 = blockIdx.y * 128;
  const int wm = (wave >> 1) * 64;
  const int wn = (wave & 1) * 64;

  f32x4 acc[4][4] = {};

  for (int k0 = 0; k0 < K; k0 += 32) {
    // stage 128x32 A-tile and W-tile: 512 x 16B chunks each, lane-contiguous
#pragma unroll
    for (int hh = 0; hh < 2; ++hh) {
      int c = tid + hh * 256;
      int row = c >> 2, part = c & 3;
      g2lds16(A + (size_t)(m0 + row) * K + (k0 + part * 8), As + c * 8);
      g2lds16(W + (size_t)(n0 + row) * K + (k0 + part * 8), Ws + c * 8);
    }
    __syncthreads();  // drains vmcnt -> LDS valid
    bf16x8 af[4], bfr[4];
#pragma unroll
    for (int t = 0; t < 4; ++t)
      af[t] = *(const bf16x8*)(As + (wm + t * 16 + (lane & 15)) * 32 + (lane >> 4) * 8);
#pragma unroll
    for (int t = 0; t < 4; ++t)
      bfr[t] = *(const bf16x8*)(Ws + (wn + t * 16 + (lane & 15)) * 32 + (lane >> 4) * 8);
#pragma unroll
    for (int mi = 0; mi < 4; ++mi)
#pragma unroll
      for (int ni = 0; ni < 4; ++ni)
        acc[mi][ni] = __builtin_amdgcn_mfma_f32_16x16x32_bf16(af[mi], bfr[ni], acc[mi][ni], 0, 0, 0);
    __syncthreads();
  }

  // epilogue: C/D layout col = lane&15, row = (lane>>4)*4 + r
#pragma unroll
  for (int mi = 0; mi < 4; ++mi) {
#pragma unroll
    for (int ni = 0; ni < 4; ++ni) {
      int col = n0 + wn + ni * 16 + (lane & 15);
      float bv = bias ? bias[col] : 0.f;
#pragma unroll
      for (int r = 0; r < 4; ++r) {
        int row = m0 + wm + mi * 16 + (lane >> 4) * 4 + r;
        float vv = acc[mi][ni][r] + bv;
        if (relu) vv = fmaxf(vv, 0.f);
        C[(size_t)row * Nn + col] = vv;
      }
    }
  }
}

// ---------------------------------------------------------------------------
// Banded attention: one wave per row i, 4 rows/block. Coalesced float4 Q/K
// loads, butterfly-shuffle dot reduction, softmax over |i-j|<20.
// Q at QKV[:, qoff:], K at QKV[:, koff:]; logits scaled by `scale`.
// ---------------------------------------------------------------------------
template <int DIM>
__global__ __launch_bounds__(256) void banded_attn(
    const float* __restrict__ QKV, int ld, int qoff, int koff,
    float* __restrict__ attBase, float* __restrict__ band,
    int N, int attStride, int colOff, float scale) {
  const int lane = threadIdx.x & 63;
  const int wave = threadIdx.x >> 6;
  const int i = blockIdx.x * 4 + wave;
  const int lo = imax(i - 19, 0);
  const int hi = imin(i + 19, N - 1);
  const int nj = hi - lo + 1;
  constexpr int C4 = DIM / 256;  // float4 chunks per lane (video: 4, audio: 0)
  float logit = 0.f;

  if constexpr (C4 > 0) {
    f32x4 q[C4];
    const float* qrow = QKV + (size_t)i * ld + qoff;
#pragma unroll
    for (int c = 0; c < C4; ++c) q[c] = *(const f32x4*)(qrow + c * 256 + lane * 4);
#pragma unroll 1
    for (int s = 0; s < nj; ++s) {
      const float* kr = QKV + (size_t)(lo + s) * ld + koff;
      float p = 0.f;
#pragma unroll
      for (int c = 0; c < C4; ++c) {
        f32x4 k = *(const f32x4*)(kr + c * 256 + lane * 4);
        p += q[c].x * k.x + q[c].y * k.y + q[c].z * k.z + q[c].w * k.w;
      }
#pragma unroll
      for (int off = 32; off; off >>= 1) p += __shfl_xor(p, off);
      if (lane == s) logit = p;
    }
  } else {
    f32x2 q = *(const f32x2*)(QKV + (size_t)i * ld + qoff + lane * 2);
#pragma unroll 1
    for (int s = 0; s < nj; ++s) {
      f32x2 k = *(const f32x2*)(QKV + (size_t)(lo + s) * ld + koff + lane * 2);
      float p = q.x * k.x + q.y * k.y;
#pragma unroll
      for (int off = 32; off; off >>= 1) p += __shfl_xor(p, off);
      if (lane == s) logit = p;
    }
  }

  logit *= scale;
  float v = (lane < nj) ? logit : -3.4e38f;
  float mx = v;
#pragma unroll
  for (int off = 32; off; off >>= 1) mx = fmaxf(mx, __shfl_xor(mx, off));
  float e = (lane < nj) ? __expf(v - mx) : 0.f;
  float den = e;
#pragma unroll
  for (int off = 32; off; off >>= 1) den += __shfl_xor(den, off);
  float att = e / den;
  if (lane < nj) {
    attBase[(size_t)i * attStride + colOff + lo + lane] = att;
    band[i * 40 + lane] = att;
  }
}

// ---------------------------------------------------------------------------
// y[j,:] = sum_i att[i,j] * V[i,:]  (att.T @ V), band only. bf16 out.
// Video: one block (256 thr) per j, float4 per thread.
// ---------------------------------------------------------------------------
__global__ __launch_bounds__(256) void apply_attn_v(
    const float* __restrict__ QKV, int ld, int voff,
    const float* __restrict__ band, u16* __restrict__ Y, int N) {
  const int j = blockIdx.x;
  const int tid = threadIdx.x;
  __shared__ float a_sh[40];
  const int lo = imax(j - 19, 0);
  const int hi = imin(j + 19, N - 1);
  const int ni = hi - lo + 1;
  if (tid < ni) {
    int i = lo + tid;
    a_sh[tid] = band[i * 40 + (j - imax(i - 19, 0))];
  }
  __syncthreads();
  f32x4 acc = {0.f, 0.f, 0.f, 0.f};
#pragma unroll 1
  for (int s = 0; s < ni; ++s) {
    float a = a_sh[s];
    f32x4 vv = *(const f32x4*)(QKV + (size_t)(lo + s) * ld + voff + tid * 4);
    acc.x += a * vv.x;
    acc.y += a * vv.y;
    acc.z += a * vv.z;
    acc.w += a * vv.w;
  }
  s16x4 o;
  o.x = (short)f2bf(acc.x);
  o.y = (short)f2bf(acc.y);
  o.z = (short)f2bf(acc.z);
  o.w = (short)f2bf(acc.w);
  *(s16x4*)(Y + (size_t)j * 1024 + tid * 4) = o;
}

// Audio: one wave per j (4 j/block), float2 per lane.
__global__ __launch_bounds__(256) void apply_attn_a(
    const float* __restrict__ QKV, int ld, int voff,
    const float* __restrict__ band, u16* __restrict__ Y, int N) {
  const int lane = threadIdx.x & 63;
  const int wave = threadIdx.x >> 6;
  const int j = blockIdx.x * 4 + wave;
  __shared__ float a_sh[4][40];
  const int lo = imax(j - 19, 0);
  const int hi = imin(j + 19, N - 1);
  const int ni = hi - lo + 1;
  if (lane < ni) {
    int i = lo + lane;
    a_sh[wave][lane] = band[i * 40 + (j - imax(i - 19, 0))];
  }
  __syncthreads();
  f32x2 acc = {0.f, 0.f};
#pragma unroll 1
  for (int s = 0; s < ni; ++s) {
    float a = a_sh[wave][s];
    f32x2 vv = *(const f32x2*)(QKV + (size_t)(lo + s) * ld + voff + lane * 2);
    acc.x += a * vv.x;
    acc.y += a * vv.y;
  }
  u32 o = (u32)f2bf(acc.x) | ((u32)f2bf(acc.y) << 16);
  *(u32*)(Y + (size_t)j * 128 + lane * 2) = o;
}

// ---------------------------------------------------------------------------
// LayerNorm(O + X)*g + b -> bf16 at [row*outStride + outOff + c]
// Video: 256 thr, float4 per thread.
// ---------------------------------------------------------------------------
__global__ __launch_bounds__(256) void ln_res_v(
    const float* __restrict__ O, const float* __restrict__ X,
    const float* __restrict__ g, const float* __restrict__ bb,
    u16* __restrict__ out, int outStride, int outOff) {
  const int row = blockIdx.x;
  const int tid = threadIdx.x, lane = tid & 63, wave = tid >> 6;
  __shared__ float shA[4], shB[4];
  f32x4 o4 = ((const f32x4*)(O + (size_t)row * 1024))[tid];
  f32x4 x4 = ((const f32x4*)(X + (size_t)row * 1024))[tid];
  f32x4 v;
  v.x = o4.x + x4.x; v.y = o4.y + x4.y; v.z = o4.z + x4.z; v.w = o4.w + x4.w;
  float s = v.x + v.y + v.z + v.w;
  float s2 = v.x * v.x + v.y * v.y + v.z * v.z + v.w * v.w;
#pragma unroll
  for (int off = 32; off; off >>= 1) {
    s += __shfl_xor(s, off);
    s2 += __shfl_xor(s2, off);
  }
  if (lane == 0) { shA[wave] = s; shB[wave] = s2; }
  __syncthreads();
  float S = shA[0] + shA[1] + shA[2] + shA[3];
  float S2 = shB[0] + shB[1] + shB[2] + shB[3];
  float mu = S / 1024.f;
  float var = S2 / 1024.f - mu * mu;
  float inv = rsqrtf(var + 1e-6f);
  f32x4 gg = ((const f32x4*)g)[tid];
  f32x4 bv = ((const f32x4*)bb)[tid];
  s16x4 o;
  o.x = (short)f2bf((v.x - mu) * inv * gg.x + bv.x);
  o.y = (short)f2bf((v.y - mu) * inv * gg.y + bv.y);
  o.z = (short)f2bf((v.z - mu) * inv * gg.z + bv.z);
  o.w = (short)f2bf((v.w - mu) * inv * gg.w + bv.w);
  *(s16x4*)(out + (size_t)row * outStride + outOff + tid * 4) = o;
}

// Audio: 128 thr, scalar (small).
__global__ __launch_bounds__(128) void ln_res_a(
    const float* __restrict__ O, const float* __restrict__ X,
    const float* __restrict__ g, const float* __restrict__ bb,
    u16* __restrict__ out, int outStride, int outOff) {
  const int row = blockIdx.x;
  const int tid = threadIdx.x, lane = tid & 63, wave = tid >> 6;
  __shared__ float shA[2], shB[2];
  float v = O[(size_t)row * 128 + tid] + X[(size_t)row * 128 + tid];
  float s = v, s2 = v * v;
#pragma unroll
  for (int off = 32; off; off >>= 1) {
    s += __shfl_xor(s, off);
    s2 += __shfl_xor(s2, off);
  }
  if (lane == 0) { shA[wave] = s; shB[wave] = s2; }
  __syncthreads();
  float S = shA[0] + shA[1];
  float S2 = shB[0] + shB[1];
  float mu = S / 128.f;
  float var = S2 / 128.f - mu * mu;
  float inv = rsqrtf(var + 1e-6f);
  out[(size_t)row * outStride + outOff + tid] = f2bf((v - mu) * inv * g[tid] + bb[tid]);
}

// ---------------------------------------------------------------------------
// head: score[row] = sigmoid( LN(H[row]) . kw + kb )
// ---------------------------------------------------------------------------
__global__ __launch_bounds__(256) void head_kernel(
    const float* __restrict__ H, const float* __restrict__ g,
    const float* __restrict__ bb, const float* __restrict__ kw,
    const float* __restrict__ kb, float* __restrict__ score) {
  const int row = blockIdx.x;
  const int tid = threadIdx.x, lane = tid & 63, wave = tid >> 6;
  __shared__ float shA[4], shB[4];
  f32x4 v = ((const f32x4*)(H + (size_t)row * 1024))[tid];
  float s = v.x + v.y + v.z + v.w;
  float s2 = v.x * v.x + v.y * v.y + v.z * v.z + v.w * v.w;
#pragma unroll
  for (int off = 32; off; off >>= 1) {
    s += __shfl_xor(s, off);
    s2 += __shfl_xor(s2, off);
  }
  if (lane == 0) { shA[wave] = s; shB[wave] = s2; }
  __syncthreads();
  float S = shA[0] + shA[1] + shA[2] + shA[3];
  float S2 = shB[0] + shB[1] + shB[2] + shB[3];
  float mu = S / 1024.f;
  float var = S2 / 1024.f - mu * mu;
  float inv = rsqrtf(var + 1e-6f);
  f32x4 gg = ((const f32x4*)g)[tid];
  f32x4 bv = ((const f32x4*)bb)[tid];
  f32x4 kv = ((const f32x4*)kw)[tid];
  float p = ((v.x - mu) * inv * gg.x + bv.x) * kv.x +
            ((v.y - mu) * inv * gg.y + bv.y) * kv.y +
            ((v.z - mu) * inv * gg.z + bv.z) * kv.z +
            ((v.w - mu) * inv * gg.w + bv.w) * kv.w;
#pragma unroll
  for (int off = 32; off; off >>= 1) p += __shfl_xor(p, off);
  __syncthreads();
  if (lane == 0) shA[wave] = p;
  __syncthreads();
  if (tid == 0) {
    float P = shA[0] + shA[1] + shA[2] + shA[3] + kb[0];
    score[row] = 1.f / (1.f + __expf(-P));
  }
}

// ---------------------------------------------------------------------------
extern "C" void kernel_launch(void* const* d_in, const int* in_sizes, int n_in,
                              void* d_out, int out_size, void* d_ws, size_t ws_size,
                              hipStream_t stream) {
  const float* x = (const float*)d_in[0];     // [N,1024]
  const float* xa = (const float*)d_in[1];    // [N,128]
  const float* Wk_v = (const float*)d_in[4];
  const float* Wq_v = (const float*)d_in[5];
  const float* Wv_v = (const float*)d_in[6];
  const float* Wo_v = (const float*)d_in[7];
  const float* Wk_a = (const float*)d_in[8];
  const float* Wq_a = (const float*)d_in[9];
  const float* Wv_a = (const float*)d_in[10];
  const float* Wo_a = (const float*)d_in[11];
  const float* ka_w = (const float*)d_in[12];  // [1024,1152]
  const float* ka_b = (const float*)d_in[13];
  const float* kd_w = (const float*)d_in[14];  // [1,1024]
  const float* kd_b = (const float*)d_in[15];
  const float* ln_y_g = (const float*)d_in[16];
  const float* ln_y_b = (const float*)d_in[17];
  const float* ln_ya_g = (const float*)d_in[18];
  const float* ln_ya_b = (const float*)d_in[19];
  const float* ln_ka_g = (const float*)d_in[20];
  const float* ln_ka_b = (const float*)d_in[21];

  const int N = in_sizes[0] / 1024;  // 6144
  const int MV = 1024, MA = 128, MH = 1152;

  char* wsb = (char*)d_ws;
  size_t off = 0;
  auto alloc = [&](size_t bytes) -> void* {
    void* p = wsb + off;
    off += (bytes + 255) & ~(size_t)255;
    return p;
  };
  u16* xf_b   = (u16*)alloc((size_t)N * MV * 2);
  u16* xa_b   = (u16*)alloc((size_t)N * MA * 2);
  u16* wqkv_b = (u16*)alloc((size_t)3 * MV * MV * 2);   // [K;Q;V] rows
  u16* wqkva_b= (u16*)alloc((size_t)3 * MA * MA * 2);
  u16* wov_b  = (u16*)alloc((size_t)MV * MV * 2);
  u16* woa_b  = (u16*)alloc((size_t)MA * MA * 2);
  u16* kaw_b  = (u16*)alloc((size_t)1024 * MH * 2);
  float* QKVv = (float*)alloc((size_t)N * 3 * MV * 4);  // cols: K|Q|V
  float* QKVa = (float*)alloc((size_t)N * 3 * MA * 4);
  float* bandV = (float*)alloc((size_t)N * 40 * 4);
  float* bandA = (float*)alloc((size_t)N * 40 * 4);
  u16* yv_b = (u16*)alloc((size_t)N * MV * 2);
  u16* ya_b = (u16*)alloc((size_t)N * MA * 2);
  float* ov = (float*)alloc((size_t)N * MV * 4);  // reused as h after LN
  float* oa = (float*)alloc((size_t)N * MA * 4);
  u16* ycomb_b = (u16*)alloc((size_t)N * MH * 2);
  float* h = ov;  // ov fully consumed by ln_res_v before h GEMM (stream-ordered)

  float* dout = (float*)d_out;
  float* attBase = dout + N;  // att_comb [N, 2N]

  // 1) zero d_out (att outside band must be 0; fill hits ~6.3 TB/s)
  hipMemsetAsync(d_out, 0, (size_t)out_size * sizeof(float), stream);

  // 2) casts to bf16
  auto cast = [&](const float* src, u16* dst, size_t n) {
    int n4 = (int)(n / 4);
    cast_kernel<<<(n4 + 255) / 256, 256, 0, stream>>>(src, dst, n4);
  };
  cast(x, xf_b, (size_t)N * MV);
  cast(xa, xa_b, (size_t)N * MA);
  cast(Wo_v, wov_b, (size_t)MV * MV);
  cast(Wo_a, woa_b, (size_t)MA * MA);
  cast(ka_w, kaw_b, (size_t)1024 * MH);
  {
    int n4 = MV * MV / 4;
    cast3_kernel<<<(3 * n4 + 255) / 256, 256, 0, stream>>>(Wk_v, Wq_v, Wv_v, wqkv_b, n4);
  }
  {
    int n4 = MA * MA / 4;
    cast3_kernel<<<(3 * n4 + 255) / 256, 256, 0, stream>>>(Wk_a, Wq_a, Wv_a, wqkva_b, n4);
  }

  // 3) fused QKV projections (Q-scale 0.06 folded into logits)
  dim3 gv(N / 128, 3 * MV / 128);   // 48 x 24
  dim3 ga(N / 128, 3 * MA / 128);   // 48 x 3
  gemm_bf16<<<gv, 256, 0, stream>>>(xf_b, wqkv_b, QKVv, nullptr, N, 3 * MV, MV, 0);
  gemm_bf16<<<ga, 256, 0, stream>>>(xa_b, wqkva_b, QKVa, nullptr, N, 3 * MA, MA, 0);

  // 4) banded softmax attention (att scatter into d_out + dense band buffer)
  banded_attn<1024><<<N / 4, 256, 0, stream>>>(QKVv, 3 * MV, MV, 0, attBase, bandV, N, 2 * N, 0, 0.06f);
  banded_attn<128><<<N / 4, 256, 0, stream>>>(QKVa, 3 * MA, MA, 0, attBase, bandA, N, 2 * N, N, 0.06f);

  // 5) y = att.T @ V  (bf16 out)
  apply_attn_v<<<N, 256, 0, stream>>>(QKVv, 3 * MV, 2 * MV, bandV, yv_b, N);
  apply_attn_a<<<N / 4, 256, 0, stream>>>(QKVa, 3 * MA, 2 * MA, bandA, ya_b, N);

  // 6) output projections
  dim3 gov(N / 128, MV / 128);
  dim3 goa(N / 128, MA / 128);
  gemm_bf16<<<gov, 256, 0, stream>>>(yv_b, wov_b, ov, nullptr, N, MV, MV, 0);
  gemm_bf16<<<goa, 256, 0, stream>>>(ya_b, woa_b, oa, nullptr, N, MA, MA, 0);

  // 7) LN(o + x) -> ycomb (bf16, concat columns)
  ln_res_v<<<N, 256, 0, stream>>>(ov, x, ln_y_g, ln_y_b, ycomb_b, MH, 0);
  ln_res_a<<<N, 128, 0, stream>>>(oa, xa, ln_ya_g, ln_ya_b, ycomb_b, MH, 1024);

  // 8) h = relu(ycomb @ ka_w.T + ka_b)
  dim3 gh(N / 128, 1024 / 128);
  gemm_bf16<<<gh, 256, 0, stream>>>(ycomb_b, kaw_b, h, ka_b, N, 1024, MH, 1);

  // 9) score = sigmoid(LN(h) . kd_w + kd_b)
  head_kernel<<<N, 256, 0, stream>>>(h, ln_ka_g, ln_ka_b, kd_w, kd_b, dout);
}